// Round 1
// baseline (182.670 us; speedup 1.0000x reference)
//
#include <hip/hip_runtime.h>
#include <stdint.h>

// Problem constants
// B=2, S=2048, D=1024, H=16, DH=64; M = B*S = 4096.

typedef __attribute__((ext_vector_type(8))) short s16x8;   // 8 bf16 (MFMA A/B frag)
typedef __attribute__((ext_vector_type(4))) float fx4;     // MFMA C/D frag
typedef __attribute__((ext_vector_type(4))) unsigned int ux4;
typedef __attribute__((ext_vector_type(2))) unsigned int ux2;

__device__ __forceinline__ unsigned short f2bf(float x) {
  unsigned u = __builtin_bit_cast(unsigned, x);
  u += 0x7fffu + ((u >> 16) & 1u);          // RNE
  return (unsigned short)(u >> 16);
}
__device__ __forceinline__ float bf2f(unsigned short h) {
  return __builtin_bit_cast(float, (unsigned)h << 16);
}

// async global->LDS, 16B per lane; LDS dest = wave-uniform base + lane*16
__device__ __forceinline__ void gload_lds16(const void* g, void* l) {
  __builtin_amdgcn_global_load_lds(
      (const __attribute__((address_space(1))) unsigned int*)g,
      (__attribute__((address_space(3))) unsigned int*)l, 16, 0, 0);
}

// ---------------- conversion: f32 -> bf16 ----------------
__global__ void k_conv_bf16(const float* __restrict__ X,
                            unsigned short* __restrict__ Y, int n4) {
  int stride = gridDim.x * blockDim.x;
  for (int i = blockIdx.x * blockDim.x + threadIdx.x; i < n4; i += stride) {
    fx4 v = *(const fx4*)(X + (size_t)i * 4);
    ux2 o;
    o[0] = (unsigned)f2bf(v[0]) | ((unsigned)f2bf(v[1]) << 16);
    o[1] = (unsigned)f2bf(v[2]) | ((unsigned)f2bf(v[3]) << 16);
    *(ux2*)(Y + (size_t)i * 4) = o;
  }
}

// ---------------- transpose + convert: W[k][n] f32 -> Wt[n][k] bf16 ----------------
__global__ void k_transpose_w(const float* __restrict__ W0, const float* __restrict__ W1,
                              const float* __restrict__ W2, const float* __restrict__ W3,
                              unsigned short* __restrict__ T0, unsigned short* __restrict__ T1,
                              unsigned short* __restrict__ T2, unsigned short* __restrict__ T3) {
  const float* W = blockIdx.z == 0 ? W0 : blockIdx.z == 1 ? W1 : blockIdx.z == 2 ? W2 : W3;
  unsigned short* T = blockIdx.z == 0 ? T0 : blockIdx.z == 1 ? T1 : blockIdx.z == 2 ? T2 : T3;
  __shared__ float t[32][33];
  int bx = blockIdx.x * 32, by = blockIdx.y * 32;
  int tx = threadIdx.x, ty = threadIdx.y;
#pragma unroll
  for (int i = 0; i < 32; i += 8)
    t[ty + i][tx] = W[(size_t)(by + ty + i) * 1024 + bx + tx];
  __syncthreads();
#pragma unroll
  for (int i = 0; i < 32; i += 8)
    T[(size_t)(bx + ty + i) * 1024 + by + tx] = f2bf(t[tx][ty + i]);
}

// ---------------- GEMM: C[M x Ntot] = A[M x 1024] * W (W given transposed: Wt[n][k]) ----
// tile 128x128, BK=64, 256 thr (4 waves 2x2 of 64x64), mfma 16x16x32 bf16.
// LDS XOR swizzle: content LDS[row][x] = src[row][x ^ ((row&7)<<4)] (byte offsets),
// achieved by pre-swizzling the per-lane GLOBAL source for global_load_lds.
template <int OUTF32>
__global__ __launch_bounds__(256, 2)
void k_gemm_bt(const unsigned short* __restrict__ A,
               const unsigned short* __restrict__ W0,
               const unsigned short* __restrict__ W1,
               const unsigned short* __restrict__ W2,
               void* __restrict__ Cptr, int ldc) {
  __shared__ unsigned short As[128 * 64];
  __shared__ unsigned short Bs[128 * 64];
  const int tid = threadIdx.x;
  const int w = tid >> 6, l = tid & 63;
  const int lr = l & 15, lg = l >> 4;
  const int wm = w >> 1, wn = w & 1;
  const int m0 = blockIdx.x * 128;
  const int nt = blockIdx.y;
  const unsigned short* Bt = (nt < 8) ? W0 : (nt < 16) ? W1 : W2;
  const int n0 = (nt & 7) * 128;

  fx4 acc[4][4] = {};

  const int srow = w * 8 + (l >> 3);              // row within a 32-row issue block
  const int skb  = ((l & 7) ^ (l >> 3)) * 8;      // pre-swizzled 16B slot (elements)
  const unsigned short* aB = A  + (size_t)(m0 + srow) * 1024 + skb;
  const unsigned short* bB = Bt + (size_t)(n0 + srow) * 1024 + skb;
  unsigned short* aD = &As[w * 512];
  unsigned short* bD = &Bs[w * 512];
  const int rdswz = (l & 7) << 4;

  for (int kt = 0; kt < 1024; kt += 64) {
    __syncthreads();
#pragma unroll
    for (int j = 0; j < 4; ++j) {
      gload_lds16(aB + j * 32768 + kt, aD + j * 2048);
      gload_lds16(bB + j * 32768 + kt, bD + j * 2048);
    }
    __syncthreads();
#pragma unroll
    for (int ks = 0; ks < 2; ++ks) {
      const int kb = (ks * 64 + lg * 16) ^ rdswz;
      s16x8 af[4], bf[4];
#pragma unroll
      for (int mf = 0; mf < 4; ++mf)
        af[mf] = *(const s16x8*)((const char*)As + (wm * 64 + mf * 16 + lr) * 128 + kb);
#pragma unroll
      for (int nf = 0; nf < 4; ++nf)
        bf[nf] = *(const s16x8*)((const char*)Bs + (wn * 64 + nf * 16 + lr) * 128 + kb);
#pragma unroll
      for (int mf = 0; mf < 4; ++mf)
#pragma unroll
        for (int nf = 0; nf < 4; ++nf)
          acc[mf][nf] = __builtin_amdgcn_mfma_f32_16x16x32_bf16(af[mf], bf[nf], acc[mf][nf], 0, 0, 0);
    }
  }

  // C/D layout: row = (l>>4)*4 + reg, col = l&15  [m89/m91-verified]
  const int gn = nt * 128 + wn * 64;
  const int gm = m0 + wm * 64;
#pragma unroll
  for (int mf = 0; mf < 4; ++mf)
#pragma unroll
    for (int r = 0; r < 4; ++r) {
      int row = gm + mf * 16 + lg * 4 + r;
      if (OUTF32) {
        float* C = (float*)Cptr + (size_t)row * ldc + gn;
#pragma unroll
        for (int nf = 0; nf < 4; ++nf) C[nf * 16 + lr] = acc[mf][nf][r];
      } else {
        unsigned short* C = (unsigned short*)Cptr + (size_t)row * ldc + gn;
#pragma unroll
        for (int nf = 0; nf < 4; ++nf) C[nf * 16 + lr] = f2bf(acc[mf][nf][r]);
      }
    }
}

// ---------------- RMSNorm over DH=64 + layout split to [B*H][S][64] -------------
// q additionally scaled by 0.125 (attention scale folded in; exact in bf16).
__global__ __launch_bounds__(256)
void k_rms_split(const unsigned short* __restrict__ QKV,
                 unsigned short* __restrict__ qn, unsigned short* __restrict__ kn,
                 unsigned short* __restrict__ vb) {
  int t = blockIdx.x * 256 + threadIdx.x;
  int unit = t >> 3, sl = t & 7;     // 8 lanes x 8 elems = 64 per (tensor,b,s,h)
  int tz = unit >> 16;               // 0=q 1=k 2=v
  int r = unit & 0xffff;
  int bs = r >> 4, h = r & 15;
  const unsigned short* src = QKV + (size_t)bs * 3072 + tz * 1024 + h * 64 + sl * 8;
  ux4 dv = *(const ux4*)src;
  float f[8];
#pragma unroll
  for (int i = 0; i < 4; ++i) {
    f[2 * i]     = bf2f((unsigned short)(dv[i] & 0xffff));
    f[2 * i + 1] = bf2f((unsigned short)(dv[i] >> 16));
  }
  float ss = 0.f;
#pragma unroll
  for (int i = 0; i < 8; ++i) ss += f[i] * f[i];
  ss += __shfl_xor(ss, 1);
  ss += __shfl_xor(ss, 2);
  ss += __shfl_xor(ss, 4);
  float scale = 1.0f;
  if (tz != 2) {
    scale = rsqrtf(ss * (1.0f / 64.0f) + 1e-6f);
    if (tz == 0) scale *= 0.125f;
  }
  ux4 o;
#pragma unroll
  for (int i = 0; i < 4; ++i)
    o[i] = (unsigned)f2bf(f[2 * i] * scale) | ((unsigned)f2bf(f[2 * i + 1] * scale) << 16);
  int b = bs >> 11, s = bs & 2047;
  unsigned short* dst = (tz == 0 ? qn : tz == 1 ? kn : vb)
                        + ((size_t)((b << 4) + h) * 2048 + s) * 64 + sl * 8;
  *(ux4*)dst = o;
}

// ---------------- flash attention (causal), bf16 in/out ----------------
// grid 512 blocks: id = tq_perm*32 + bh; 4 waves x 32 q-rows; KVBLK=64.
__global__ __launch_bounds__(256, 2)
void k_attn(const unsigned short* __restrict__ Q,   // [32][2048][64], pre-scaled
            const unsigned short* __restrict__ K,
            const unsigned short* __restrict__ V,
            unsigned short* __restrict__ O) {       // [2][2048][1024]
  __shared__ unsigned short Ks[64 * 64];        // [kv][dh], XOR-swizzled rows
  __shared__ unsigned short Vt[64 * 72];        // [dh][kv], stride 72 (144B, 2-way banks)
  __shared__ unsigned short Ps[4][32 * 72];     // per-wave P, stride 72

  const int id = blockIdx.x;
  const int bh = id & 31;
  const int traw = id >> 5;                     // 0..15
  const int tq = (traw < 8) ? (2 * traw) : (31 - 2 * traw);  // work-balance pairing
  const int q0 = tq * 128;
  const int tid = threadIdx.x;
  const int w = tid >> 6, l = tid & 63;
  const int lr = l & 15, lg = l >> 4;
  const int qw = q0 + w * 32;

  const unsigned short* Qb = Q + ((size_t)bh * 2048 + qw) * 64;
  const unsigned short* Kb = K + (size_t)bh * 2048 * 64;
  const unsigned short* Vb = V + (size_t)bh * 2048 * 64;

  // hoisted Q fragments: rows mf*16+lr, k bytes ks*64 + lg*16
  s16x8 aq[2][2];
#pragma unroll
  for (int mf = 0; mf < 2; ++mf)
#pragma unroll
    for (int ks = 0; ks < 2; ++ks)
      aq[mf][ks] = *(const s16x8*)(Qb + (mf * 16 + lr) * 64 + ks * 32 + lg * 8);

  float mx[2][4], lsum[2][4];
  fx4 oacc[2][4] = {};
#pragma unroll
  for (int mf = 0; mf < 2; ++mf)
#pragma unroll
    for (int r = 0; r < 4; ++r) { mx[mf][r] = -1e30f; lsum[mf][r] = 0.f; }

  const int ksrow = w * 8 + (l >> 3);
  const int kskb = ((l & 7) ^ (l >> 3)) * 8;    // pre-swizzled slot
  const int vkvp = tid & 31;                    // kv pair (2 kv)
  const int vdhg = tid >> 5;                    // dh group (8 dh)
  const int rdswz = (l & 7) << 4;

  const int ntiles = 2 * (tq + 1);
  for (int t = 0; t < ntiles; ++t) {
    const int kv0 = t * 64;
    __syncthreads();
    // stage K via global_load_lds (swizzled source), 2 issues of 4KB
#pragma unroll
    for (int j = 0; j < 2; ++j)
      gload_lds16(Kb + (size_t)(kv0 + j * 32 + ksrow) * 64 + kskb, &Ks[j * 2048 + w * 512]);
    // stage V transposed: each thread 2kv x 8dh
    {
      const unsigned short* vsrc = Vb + (size_t)(kv0 + vkvp * 2) * 64 + vdhg * 8;
      union { ux4 v; unsigned short u[8]; } a0, a1;
      a0.v = *(const ux4*)vsrc;
      a1.v = *(const ux4*)(vsrc + 64);
#pragma unroll
      for (int i = 0; i < 8; ++i) {
        unsigned pk = (unsigned)a0.u[i] | ((unsigned)a1.u[i] << 16);
        *(unsigned*)((char*)Vt + (vdhg * 8 + i) * 144 + vkvp * 4) = pk;
      }
    }
    __syncthreads();

    if (kv0 <= qw + 31) {                       // tile has unmasked work for this wave
      fx4 sc[2][4] = {};
#pragma unroll
      for (int ks = 0; ks < 2; ++ks) {
        const int kb = (ks * 64 + lg * 16) ^ rdswz;
        s16x8 bk[4];
#pragma unroll
        for (int nf = 0; nf < 4; ++nf)
          bk[nf] = *(const s16x8*)((const char*)Ks + (nf * 16 + lr) * 128 + kb);
#pragma unroll
        for (int mf = 0; mf < 2; ++mf)
#pragma unroll
          for (int nf = 0; nf < 4; ++nf)
            sc[mf][nf] = __builtin_amdgcn_mfma_f32_16x16x32_bf16(aq[mf][ks], bk[nf], sc[mf][nf], 0, 0, 0);
      }
      if (kv0 + 63 > qw) {                      // causal boundary tile
#pragma unroll
        for (int mf = 0; mf < 2; ++mf)
#pragma unroll
          for (int nf = 0; nf < 4; ++nf)
#pragma unroll
            for (int r = 0; r < 4; ++r) {
              int gq = qw + mf * 16 + lg * 4 + r;
              int gk = kv0 + nf * 16 + lr;
              if (gk > gq) sc[mf][nf][r] = -1e30f;
            }
      }
      // online softmax (16-lane group shfl reduce); write P to per-wave LDS
#pragma unroll
      for (int mf = 0; mf < 2; ++mf) {
        unsigned short* pp = &Ps[w][(mf * 16 + lg * 4) * 72];
#pragma unroll
        for (int r = 0; r < 4; ++r) {
          float v0 = sc[mf][0][r], v1 = sc[mf][1][r], v2 = sc[mf][2][r], v3 = sc[mf][3][r];
          float rm = fmaxf(fmaxf(v0, v1), fmaxf(v2, v3));
          rm = fmaxf(rm, __shfl_xor(rm, 1));
          rm = fmaxf(rm, __shfl_xor(rm, 2));
          rm = fmaxf(rm, __shfl_xor(rm, 4));
          rm = fmaxf(rm, __shfl_xor(rm, 8));
          float mo = mx[mf][r];
          float mn = fmaxf(mo, rm);
          mx[mf][r] = mn;
          float corr = __expf(mo - mn);
          float p0 = __expf(v0 - mn), p1 = __expf(v1 - mn);
          float p2 = __expf(v2 - mn), p3 = __expf(v3 - mn);
          float rs = (p0 + p1) + (p2 + p3);
          rs += __shfl_xor(rs, 1);
          rs += __shfl_xor(rs, 2);
          rs += __shfl_xor(rs, 4);
          rs += __shfl_xor(rs, 8);
          lsum[mf][r] = lsum[mf][r] * corr + rs;
#pragma unroll
          for (int nf = 0; nf < 4; ++nf) oacc[mf][nf][r] *= corr;
          unsigned short* prow = pp + r * 72;
          prow[lr]      = f2bf(p0);
          prow[lr + 16] = f2bf(p1);
          prow[lr + 32] = f2bf(p2);
          prow[lr + 48] = f2bf(p3);
        }
      }
      // PV: A = P (rows mf*16+lr), B = V via Vt[dh][kv]
#pragma unroll
      for (int ks = 0; ks < 2; ++ks) {
        s16x8 pa[2], bv[4];
#pragma unroll
        for (int mf = 0; mf < 2; ++mf)
          pa[mf] = *(const s16x8*)((const char*)&Ps[w][0] + (mf * 16 + lr) * 144 + ks * 64 + lg * 16);
#pragma unroll
        for (int nf = 0; nf < 4; ++nf)
          bv[nf] = *(const s16x8*)((const char*)Vt + (nf * 16 + lr) * 144 + ks * 64 + lg * 16);
#pragma unroll
        for (int mf = 0; mf < 2; ++mf)
#pragma unroll
          for (int nf = 0; nf < 4; ++nf)
            oacc[mf][nf] = __builtin_amdgcn_mfma_f32_16x16x32_bf16(pa[mf], bv[nf], oacc[mf][nf], 0, 0, 0);
      }
    }
  }

  // epilogue: O[b][s][h*64+dh] bf16
  const int b = bh >> 4, h = bh & 15;
#pragma unroll
  for (int mf = 0; mf < 2; ++mf)
#pragma unroll
    for (int r = 0; r < 4; ++r) {
      float inv = 1.0f / lsum[mf][r];
      int gs = qw + mf * 16 + lg * 4 + r;
      unsigned short* orow = O + ((size_t)(b * 2048 + gs)) * 1024 + h * 64;
#pragma unroll
      for (int nf = 0; nf < 4; ++nf)
        orow[nf * 16 + lr] = f2bf(oacc[mf][nf][r] * inv);
    }
}

// ---------------- launch ----------------
extern "C" void kernel_launch(void* const* d_in, const int* in_sizes, int n_in,
                              void* d_out, int out_size, void* d_ws, size_t ws_size,
                              hipStream_t stream) {
  const float* x  = (const float*)d_in[0];
  const float* Wq = (const float*)d_in[1];
  const float* Wk = (const float*)d_in[2];
  const float* Wv = (const float*)d_in[3];
  const float* Wo = (const float*)d_in[4];
  // d_in[5] = causal mask (tril) — implemented analytically.

  char* ws = (char*)d_ws;                                  // needs 72 MB
  unsigned short* xb   = (unsigned short*)(ws);            // 8 MB  [4096][1024]
  unsigned short* WqT  = (unsigned short*)(ws + (8ll  << 20));
  unsigned short* WkT  = (unsigned short*)(ws + (10ll << 20));
  unsigned short* WvT  = (unsigned short*)(ws + (12ll << 20));
  unsigned short* WoT  = (unsigned short*)(ws + (14ll << 20));
  unsigned short* QKV  = (unsigned short*)(ws + (16ll << 20)); // 24 MB [4096][3072]
  unsigned short* qn   = (unsigned short*)(ws + (40ll << 20)); // 8 MB [32][2048][64]
  unsigned short* kn   = (unsigned short*)(ws + (48ll << 20));
  unsigned short* vb   = (unsigned short*)(ws + (56ll << 20));
  unsigned short* attn = (unsigned short*)(ws + (64ll << 20)); // 8 MB [4096][1024]

  k_conv_bf16<<<1024, 256, 0, stream>>>(x, xb, 4096 * 1024 / 4);
  k_transpose_w<<<dim3(32, 32, 4), dim3(32, 8), 0, stream>>>(Wq, Wk, Wv, Wo, WqT, WkT, WvT, WoT);
  k_gemm_bt<0><<<dim3(32, 24), 256, 0, stream>>>(xb, WqT, WkT, WvT, (void*)QKV, 3072);
  k_rms_split<<<6144, 256, 0, stream>>>(QKV, qn, kn, vb);
  k_attn<<<512, 256, 0, stream>>>(qn, kn, vb, attn);
  k_gemm_bt<1><<<dim3(32, 8), 256, 0, stream>>>(attn, WoT, WoT, WoT, d_out, 1024);
}

// Round 2
// 114.471 us; speedup vs baseline: 1.5958x; 1.5958x over previous
//
#include <hip/hip_runtime.h>
#include <stdint.h>

// Problem constants
// B=2, S=2048, D=1024, H=16, DH=64; M = B*S = 4096.

typedef __attribute__((ext_vector_type(8))) short s16x8;   // 8 bf16 (MFMA A/B frag)
typedef __attribute__((ext_vector_type(4))) float fx4;     // MFMA C/D frag
typedef __attribute__((ext_vector_type(4))) unsigned int ux4;
typedef __attribute__((ext_vector_type(2))) unsigned int ux2;

__device__ __forceinline__ unsigned short f2bf(float x) {
  unsigned u = __builtin_bit_cast(unsigned, x);
  u += 0x7fffu + ((u >> 16) & 1u);          // RNE
  return (unsigned short)(u >> 16);
}
__device__ __forceinline__ float bf2f(unsigned short h) {
  return __builtin_bit_cast(float, (unsigned)h << 16);
}

// async global->LDS, 16B per lane; LDS dest = wave-uniform base + lane*16
__device__ __forceinline__ void gload_lds16(const void* g, void* l) {
  __builtin_amdgcn_global_load_lds(
      (const __attribute__((address_space(1))) unsigned int*)g,
      (__attribute__((address_space(3))) unsigned int*)l, 16, 0, 0);
}

// ---------------- conversion: f32 -> bf16 ----------------
__global__ void k_conv_bf16(const float* __restrict__ X,
                            unsigned short* __restrict__ Y, int n4) {
  int stride = gridDim.x * blockDim.x;
  for (int i = blockIdx.x * blockDim.x + threadIdx.x; i < n4; i += stride) {
    fx4 v = *(const fx4*)(X + (size_t)i * 4);
    ux2 o;
    o[0] = (unsigned)f2bf(v[0]) | ((unsigned)f2bf(v[1]) << 16);
    o[1] = (unsigned)f2bf(v[2]) | ((unsigned)f2bf(v[3]) << 16);
    *(ux2*)(Y + (size_t)i * 4) = o;
  }
}

// ---------------- transpose + convert: W[k][n] f32 -> Wt[n][k] bf16 ----------------
__global__ void k_transpose_w(const float* __restrict__ W0, const float* __restrict__ W1,
                              const float* __restrict__ W2, const float* __restrict__ W3,
                              unsigned short* __restrict__ T0, unsigned short* __restrict__ T1,
                              unsigned short* __restrict__ T2, unsigned short* __restrict__ T3) {
  const float* W = blockIdx.z == 0 ? W0 : blockIdx.z == 1 ? W1 : blockIdx.z == 2 ? W2 : W3;
  unsigned short* T = blockIdx.z == 0 ? T0 : blockIdx.z == 1 ? T1 : blockIdx.z == 2 ? T2 : T3;
  __shared__ float t[32][33];
  int bx = blockIdx.x * 32, by = blockIdx.y * 32;
  int tx = threadIdx.x, ty = threadIdx.y;
#pragma unroll
  for (int i = 0; i < 32; i += 8)
    t[ty + i][tx] = W[(size_t)(by + ty + i) * 1024 + bx + tx];
  __syncthreads();
#pragma unroll
  for (int i = 0; i < 32; i += 8)
    T[(size_t)(bx + ty + i) * 1024 + by + tx] = f2bf(t[tx][ty + i]);
}

// ---------------- GEMM: C[M x Ntot] = A[M x 1024] * W (W given transposed: Wt[n][k]) ----
// tile 128x128, BK=64, 256 thr (4 waves 2x2 of 64x64), mfma 16x16x32 bf16.
template <int OUTF32>
__global__ __launch_bounds__(256, 2)
void k_gemm_bt(const unsigned short* __restrict__ A,
               const unsigned short* __restrict__ W0,
               const unsigned short* __restrict__ W1,
               const unsigned short* __restrict__ W2,
               void* __restrict__ Cptr, int ldc) {
  __shared__ unsigned short As[128 * 64];
  __shared__ unsigned short Bs[128 * 64];
  const int tid = threadIdx.x;
  const int w = tid >> 6, l = tid & 63;
  const int lr = l & 15, lg = l >> 4;
  const int wm = w >> 1, wn = w & 1;
  const int m0 = blockIdx.x * 128;
  const int nt = blockIdx.y;
  const unsigned short* Bt = (nt < 8) ? W0 : (nt < 16) ? W1 : W2;
  const int n0 = (nt & 7) * 128;

  fx4 acc[4][4] = {};

  const int srow = w * 8 + (l >> 3);              // row within a 32-row issue block
  const int skb  = ((l & 7) ^ (l >> 3)) * 8;      // pre-swizzled 16B slot (elements)
  const unsigned short* aB = A  + (size_t)(m0 + srow) * 1024 + skb;
  const unsigned short* bB = Bt + (size_t)(n0 + srow) * 1024 + skb;
  unsigned short* aD = &As[w * 512];
  unsigned short* bD = &Bs[w * 512];
  const int rdswz = (l & 7) << 4;

  for (int kt = 0; kt < 1024; kt += 64) {
    __syncthreads();
#pragma unroll
    for (int j = 0; j < 4; ++j) {
      gload_lds16(aB + j * 32768 + kt, aD + j * 2048);
      gload_lds16(bB + j * 32768 + kt, bD + j * 2048);
    }
    __syncthreads();
#pragma unroll
    for (int ks = 0; ks < 2; ++ks) {
      const int kb = (ks * 64 + lg * 16) ^ rdswz;
      s16x8 af[4], bf[4];
#pragma unroll
      for (int mf = 0; mf < 4; ++mf)
        af[mf] = *(const s16x8*)((const char*)As + (wm * 64 + mf * 16 + lr) * 128 + kb);
#pragma unroll
      for (int nf = 0; nf < 4; ++nf)
        bf[nf] = *(const s16x8*)((const char*)Bs + (wn * 64 + nf * 16 + lr) * 128 + kb);
#pragma unroll
      for (int mf = 0; mf < 4; ++mf)
#pragma unroll
        for (int nf = 0; nf < 4; ++nf)
          acc[mf][nf] = __builtin_amdgcn_mfma_f32_16x16x32_bf16(af[mf], bf[nf], acc[mf][nf], 0, 0, 0);
    }
  }

  // C/D layout: row = (l>>4)*4 + reg, col = l&15
  const int gn = nt * 128 + wn * 64;
  const int gm = m0 + wm * 64;
#pragma unroll
  for (int mf = 0; mf < 4; ++mf)
#pragma unroll
    for (int r = 0; r < 4; ++r) {
      int row = gm + mf * 16 + lg * 4 + r;
      if (OUTF32) {
        float* C = (float*)Cptr + (size_t)row * ldc + gn;
#pragma unroll
        for (int nf = 0; nf < 4; ++nf) C[nf * 16 + lr] = acc[mf][nf][r];
      } else {
        unsigned short* C = (unsigned short*)Cptr + (size_t)row * ldc + gn;
#pragma unroll
        for (int nf = 0; nf < 4; ++nf) C[nf * 16 + lr] = f2bf(acc[mf][nf][r]);
      }
    }
}

// ---------------- RMSNorm over DH=64 + layout split to [B*H][S][64] -------------
// q additionally scaled by 0.125*log2(e) (attention scale + exp2 conversion folded).
__global__ __launch_bounds__(256)
void k_rms_split(const unsigned short* __restrict__ QKV,
                 unsigned short* __restrict__ qn, unsigned short* __restrict__ kn,
                 unsigned short* __restrict__ vb) {
  int t = blockIdx.x * 256 + threadIdx.x;
  int unit = t >> 3, sl = t & 7;     // 8 lanes x 8 elems = 64 per (tensor,b,s,h)
  int tz = unit >> 16;               // 0=q 1=k 2=v
  int r = unit & 0xffff;
  int bs = r >> 4, h = r & 15;
  const unsigned short* src = QKV + (size_t)bs * 3072 + tz * 1024 + h * 64 + sl * 8;
  ux4 dv = *(const ux4*)src;
  float f[8];
#pragma unroll
  for (int i = 0; i < 4; ++i) {
    f[2 * i]     = bf2f((unsigned short)(dv[i] & 0xffff));
    f[2 * i + 1] = bf2f((unsigned short)(dv[i] >> 16));
  }
  float ss = 0.f;
#pragma unroll
  for (int i = 0; i < 8; ++i) ss += f[i] * f[i];
  ss += __shfl_xor(ss, 1);
  ss += __shfl_xor(ss, 2);
  ss += __shfl_xor(ss, 4);
  float scale = 1.0f;
  if (tz != 2) {
    scale = rsqrtf(ss * (1.0f / 64.0f) + 1e-6f);
    if (tz == 0) scale *= 0.18033688f;   // 0.125 * log2(e)
  }
  ux4 o;
#pragma unroll
  for (int i = 0; i < 4; ++i)
    o[i] = (unsigned)f2bf(f[2 * i] * scale) | ((unsigned)f2bf(f[2 * i + 1] * scale) << 16);
  int b = bs >> 11, s = bs & 2047;
  unsigned short* dst = (tz == 0 ? qn : tz == 1 ? kn : vb)
                        + ((size_t)((b << 4) + h) * 2048 + s) * 64 + sl * 8;
  *(ux4*)dst = o;
}

// ---------------- flash attention (causal), bf16 in/out ----------------
// grid 512: id = pairIdx*32 + bh. Block handles q-tile pair (p, 31-p), 64 rows each
// -> uniform 33 KV-tiles per block. 4 waves x 16 q-rows. KVBLK=64.
// Fixed softmax max (scores bounded by 8 via RMS norm): p = exp2(s' - 8*log2e),
// no running max, no in-loop cross-lane reduce. Double-buffered K/V staging.
__global__ __launch_bounds__(256, 2)
void k_attn(const unsigned short* __restrict__ Q,   // [32][2048][64], pre-scaled by 0.125*log2e
            const unsigned short* __restrict__ K,
            const unsigned short* __restrict__ V,
            unsigned short* __restrict__ O) {       // [2][2048][1024]
  __shared__ unsigned short Ks[2][64 * 64];     // [kv][dh], XOR-swizzled rows (8KB each)
  __shared__ unsigned short Vt[2][64 * 72];     // [dh][kv], stride 72 (9KB each)
  __shared__ unsigned short Ps[4][16 * 72];     // per-wave P, stride 72

  const int id = blockIdx.x;
  const int bh = id & 31;
  const int pairIdx = id >> 5;                  // 0..15
  const int tid = threadIdx.x;
  const int w = tid >> 6, l = tid & 63;
  const int lr = l & 15, lg = l >> 4;
  const int b = bh >> 4, h = bh & 15;

  const unsigned short* Kb = K + (size_t)bh * 2048 * 64;
  const unsigned short* Vb = V + (size_t)bh * 2048 * 64;

  const int ksrow = w * 8 + (l >> 3);
  const int kskb = ((l & 7) ^ (l >> 3)) * 8;    // pre-swizzled slot
  const int vkvp = tid & 31;                    // kv pair (2 kv)
  const int vdhg = tid >> 5;                    // dh group (8 dh)
  const int rdswz = (l & 7) << 4;
  const float FMAX = 11.5415603f;               // 8 * log2(e)

#pragma unroll 1
  for (int pi = 0; pi < 2; ++pi) {
    const int tq = pi ? (31 - pairIdx) : pairIdx;
    const int q0 = tq * 64;
    const int qw = q0 + w * 16;
    const int nt = tq + 1;

    const unsigned short* Qb = Q + ((size_t)bh * 2048 + qw) * 64;
    s16x8 aq[2];
    aq[0] = *(const s16x8*)(Qb + lr * 64 + lg * 8);
    aq[1] = *(const s16x8*)(Qb + lr * 64 + 32 + lg * 8);

    fx4 oacc[4] = {};
    float lsum[4] = {0.f, 0.f, 0.f, 0.f};

    // prologue: stage tile 0 into buffer 0
    ux4 va0, va1;
#pragma unroll
    for (int j = 0; j < 2; ++j)
      gload_lds16(Kb + (size_t)(j * 32 + ksrow) * 64 + kskb, &Ks[0][j * 2048 + w * 512]);
    va0 = *(const ux4*)(Vb + (size_t)(2 * vkvp) * 64 + vdhg * 8);
    va1 = *(const ux4*)(Vb + (size_t)(2 * vkvp + 1) * 64 + vdhg * 8);
    {
      union { ux4 v; unsigned short u[8]; } a0, a1;
      a0.v = va0; a1.v = va1;
#pragma unroll
      for (int i = 0; i < 8; ++i)
        *(unsigned*)((char*)&Vt[0][0] + (vdhg * 8 + i) * 144 + vkvp * 4) =
            (unsigned)a0.u[i] | ((unsigned)a1.u[i] << 16);
    }
    __syncthreads();

#pragma unroll 1
    for (int t = 0; t < nt; ++t) {
      const int cur = t & 1;
      const int kv0 = t * 64;
      const bool pre = (t + 1 < nt);
      if (pre) {
        const int kvn = kv0 + 64;
#pragma unroll
        for (int j = 0; j < 2; ++j)
          gload_lds16(Kb + (size_t)(kvn + j * 32 + ksrow) * 64 + kskb,
                      &Ks[cur ^ 1][j * 2048 + w * 512]);
        va0 = *(const ux4*)(Vb + (size_t)(kvn + 2 * vkvp) * 64 + vdhg * 8);
        va1 = *(const ux4*)(Vb + (size_t)(kvn + 2 * vkvp + 1) * 64 + vdhg * 8);
      }
      // QK^T
      fx4 sc[4] = {};
#pragma unroll
      for (int ks = 0; ks < 2; ++ks) {
        const int kb = (ks * 64 + lg * 16) ^ rdswz;
#pragma unroll
        for (int nf = 0; nf < 4; ++nf) {
          s16x8 bk = *(const s16x8*)((const char*)&Ks[cur][0] + (nf * 16 + lr) * 128 + kb);
          sc[nf] = __builtin_amdgcn_mfma_f32_16x16x32_bf16(aq[ks], bk, sc[nf], 0, 0, 0);
        }
      }
      if (t == nt - 1) {                        // diagonal tile: causal mask
#pragma unroll
        for (int nf = 0; nf < 4; ++nf)
#pragma unroll
          for (int r = 0; r < 4; ++r) {
            int gq = qw + lg * 4 + r;
            int gk = kv0 + nf * 16 + lr;
            if (gk > gq) sc[nf][r] = -3.0e38f;
          }
      }
      // softmax with fixed max; per-lane partial sums, no cross-lane ops
      unsigned short* pw = &Ps[w][0];
#pragma unroll
      for (int r = 0; r < 4; ++r) {
        float p0 = __builtin_amdgcn_exp2f(sc[0][r] - FMAX);
        float p1 = __builtin_amdgcn_exp2f(sc[1][r] - FMAX);
        float p2 = __builtin_amdgcn_exp2f(sc[2][r] - FMAX);
        float p3 = __builtin_amdgcn_exp2f(sc[3][r] - FMAX);
        lsum[r] += (p0 + p1) + (p2 + p3);
        unsigned short* prow = pw + (lg * 4 + r) * 72;
        prow[lr]      = f2bf(p0);
        prow[lr + 16] = f2bf(p1);
        prow[lr + 32] = f2bf(p2);
        prow[lr + 48] = f2bf(p3);
      }
      // PV
#pragma unroll
      for (int ks = 0; ks < 2; ++ks) {
        s16x8 pa = *(const s16x8*)((const char*)pw + lr * 144 + ks * 64 + lg * 16);
#pragma unroll
        for (int nf = 0; nf < 4; ++nf) {
          s16x8 bv = *(const s16x8*)((const char*)&Vt[cur][0] + (nf * 16 + lr) * 144 + ks * 64 + lg * 16);
          oacc[nf] = __builtin_amdgcn_mfma_f32_16x16x32_bf16(pa, bv, oacc[nf], 0, 0, 0);
        }
      }
      if (pre) {                                // late write of next V tile
        union { ux4 v; unsigned short u[8]; } a0, a1;
        a0.v = va0; a1.v = va1;
#pragma unroll
        for (int i = 0; i < 8; ++i)
          *(unsigned*)((char*)&Vt[cur ^ 1][0] + (vdhg * 8 + i) * 144 + vkvp * 4) =
              (unsigned)a0.u[i] | ((unsigned)a1.u[i] << 16);
      }
      __syncthreads();
    }

    // epilogue: one cross-lane reduce per q-tile
#pragma unroll
    for (int r = 0; r < 4; ++r) {
      float s = lsum[r];
      s += __shfl_xor(s, 1);
      s += __shfl_xor(s, 2);
      s += __shfl_xor(s, 4);
      s += __shfl_xor(s, 8);
      float inv = 1.0f / s;
      int gq = qw + lg * 4 + r;
      unsigned short* orow = O + ((size_t)(b * 2048 + gq)) * 1024 + h * 64;
#pragma unroll
      for (int nf = 0; nf < 4; ++nf)
        orow[nf * 16 + lr] = f2bf(oacc[nf][r] * inv);
    }
  }
}

// ---------------- launch ----------------
extern "C" void kernel_launch(void* const* d_in, const int* in_sizes, int n_in,
                              void* d_out, int out_size, void* d_ws, size_t ws_size,
                              hipStream_t stream) {
  const float* x  = (const float*)d_in[0];
  const float* Wq = (const float*)d_in[1];
  const float* Wk = (const float*)d_in[2];
  const float* Wv = (const float*)d_in[3];
  const float* Wo = (const float*)d_in[4];
  // d_in[5] = causal mask (tril) — implemented analytically.

  char* ws = (char*)d_ws;                                  // needs 72 MB
  unsigned short* xb   = (unsigned short*)(ws);            // 8 MB  [4096][1024]
  unsigned short* WqT  = (unsigned short*)(ws + (8ll  << 20));
  unsigned short* WkT  = (unsigned short*)(ws + (10ll << 20));
  unsigned short* WvT  = (unsigned short*)(ws + (12ll << 20));
  unsigned short* WoT  = (unsigned short*)(ws + (14ll << 20));
  unsigned short* QKV  = (unsigned short*)(ws + (16ll << 20)); // 24 MB [4096][3072]
  unsigned short* qn   = (unsigned short*)(ws + (40ll << 20)); // 8 MB [32][2048][64]
  unsigned short* kn   = (unsigned short*)(ws + (48ll << 20));
  unsigned short* vb   = (unsigned short*)(ws + (56ll << 20));
  unsigned short* attn = (unsigned short*)(ws + (64ll << 20)); // 8 MB [4096][1024]

  k_conv_bf16<<<1024, 256, 0, stream>>>(x, xb, 4096 * 1024 / 4);
  k_transpose_w<<<dim3(32, 32, 4), dim3(32, 8), 0, stream>>>(Wq, Wk, Wv, Wo, WqT, WkT, WvT, WoT);
  k_gemm_bt<0><<<dim3(32, 24), 256, 0, stream>>>(xb, WqT, WkT, WvT, (void*)QKV, 3072);
  k_rms_split<<<6144, 256, 0, stream>>>(QKV, qn, kn, vb);
  k_attn<<<512, 256, 0, stream>>>(qn, kn, vb, attn);
  k_gemm_bt<1><<<dim3(32, 8), 256, 0, stream>>>(attn, WoT, WoT, WoT, d_out, 1024);
}